// Round 15
// baseline (270.801 us; speedup 1.0000x reference)
//
#include <hip/hip_runtime.h>
#include <hip/hip_bf16.h>

// MultiAgentGRULoop round 15: x direct global->register for layers 1-2.
//   - Layers 1,2 read x-fragments straight from ws (bf16) with per-lane
//     global_load_dwordx4: the x LDS ring, its staging copy, and 4 of the 8
//     per-thread ds_read_b128 per cell disappear (LDS pipe was co-binding:
//     ~870 cyc/CU/cell + 288 cyc of bank-conflict at R14).
//   - x frags double-buffered in NAMED even/odd register sets; gA likewise;
//     explicit 2-phase t-loop makes all indices compile-time (rule #20).
//   - Compiler vmcnt tracking orders load->x-MFMA->store; in-place ws is safe
//     because x(t) frags are consumed (waited) one cell before act(t) stores.
//   - L0 unchanged from R14 (f32 source -> staged LDS path is cheaper).
//   - Everything else R13/R14: rcp/exp2 epilogue, folded gate scaling, bf16
//     ws inter-layer acts, ballot masks, direct act stores, lgkm-only barrier.

#define T_STEPS 64
#define HID 128
#define NL 3
#define RB 16
#define NTHR 512
#define NBLK 256
#define LSTR 136   // bf16 x/h row stride (shorts): 272 B, 16B-aligned

typedef __attribute__((ext_vector_type(8))) short bf16x8;
typedef __attribute__((ext_vector_type(4))) short short4v;
typedef __attribute__((ext_vector_type(4))) float f32x4;

static __device__ __forceinline__ short f2bf_s(float f) {
  __hip_bfloat16 b = __float2bfloat16(f);
  return __builtin_bit_cast(short, b);
}
static __device__ __forceinline__ float rcp_f(float x) {
  float r; asm("v_rcp_f32 %0, %1" : "=v"(r) : "v"(x)); return r;
}
static __device__ __forceinline__ float exp2_f(float x) {
  float r; asm("v_exp_f32 %0, %1" : "=v"(r) : "v"(x)); return r;
}

#define MFMA(A, B, C) __builtin_amdgcn_mfma_f32_16x16x32_bf16((A), (B), (C), 0, 0, 0)

#define NL2E  (-1.4426950408889634f)   // -log2(e)
#define T2L2E (2.8853900817779268f)    // 2*log2(e)

// ---------------- shared helpers ----------------
struct LayerWB {
  bf16x8 wI[3][4], wH[3][4];
  f32x4 bRZ0v, bRZ1v, bNiv, bNhv;
};

__device__ __forceinline__ void load_weights(
    LayerWB& W, const float* wih, const float* whh,
    const float* bih, const float* bhh, int wave, int lr, int lq, int cb)
{
#pragma unroll
  for (int g = 0; g < 3; ++g) {
    const float sc = (g < 2) ? NL2E : T2L2E;
#pragma unroll
    for (int kf = 0; kf < 4; ++kf) {
      const int wrow = g * HID + wave * 16 + lr;
      const int kofs = kf * 32 + lq * 8;
      const float* pI = wih + (size_t)wrow * HID + kofs;
      const float* pH = whh + (size_t)wrow * HID + kofs;
      float4 a = *(const float4*)pI, b = *(const float4*)(pI + 4);
      float vi[8] = {a.x, a.y, a.z, a.w, b.x, b.y, b.z, b.w};
      float4 c = *(const float4*)pH, d = *(const float4*)(pH + 4);
      float vh[8] = {c.x, c.y, c.z, c.w, d.x, d.y, d.z, d.w};
#pragma unroll
      for (int j = 0; j < 8; ++j) {
        W.wI[g][kf][j] = f2bf_s(sc * vi[j]);
        W.wH[g][kf][j] = f2bf_s(sc * vh[j]);
      }
    }
  }
#pragma unroll
  for (int ri = 0; ri < 4; ++ri) {
    const int c = cb + ri;
    W.bRZ0v[ri] = NL2E * (bih[c] + bhh[c]);
    W.bRZ1v[ri] = NL2E * (bih[HID + c] + bhh[HID + c]);
    W.bNiv[ri]  = T2L2E * bih[2 * HID + c];
    W.bNhv[ri]  = T2L2E * bhh[2 * HID + c];
  }
}

// ---------------- L0: staged path (R14) ----------------
__device__ __forceinline__ void layer0_pass(
    const LayerWB& W, const float* srcf, unsigned short* dstb,
    unsigned mw0, unsigned mw1,
    short (*s_x)[RB * LSTR], short (*s_h)[RB * LSTR],
    int tid, int lr, int lq, int srow, int scol, int cb)
{
  for (int i = tid; i < RB * LSTR; i += NTHR) s_h[0][i] = 0;
#pragma unroll
  for (int st = 0; st < 2; ++st) {
    float4 v = *(const float4*)(srcf + (size_t)st * HID);
    short4v c4 = {f2bf_s(v.x), f2bf_s(v.y), f2bf_s(v.z), f2bf_s(v.w)};
    *(short4v*)&s_x[st][srow * LSTR + scol] = c4;
  }
  __syncthreads();

  f32x4 gA0 = W.bRZ0v, gA1 = W.bRZ1v, gAn = W.bNiv;
#pragma unroll
  for (int kf = 0; kf < 4; ++kf) {
    bf16x8 xh = *(const bf16x8*)&s_x[0][lr * LSTR + kf * 32 + lq * 8];
    gA0 = MFMA(W.wI[0][kf], xh, gA0);
    gA1 = MFMA(W.wI[1][kf], xh, gA1);
    gAn = MFMA(W.wI[2][kf], xh, gAn);
  }
  float hprev[4] = {0.f, 0.f, 0.f, 0.f};

  for (int t = 0; t < T_STEPS; ++t) {
    const int p = t & 1;
    float4 pinf;
    if (t < T_STEPS - 2)
      pinf = *(const float4*)(srcf + (size_t)(t + 2) * HID);
    const int mk = (int)((((t & 32) ? mw1 : mw0) >> (t & 31)) & 1u);

    f32x4 aH0 = (f32x4)(0.f), aH1 = (f32x4)(0.f), aHn = W.bNhv;
#pragma unroll
    for (int kf = 0; kf < 4; ++kf) {
      bf16x8 hh = *(const bf16x8*)&s_h[p][lr * LSTR + kf * 32 + lq * 8];
      aH0 = MFMA(W.wH[0][kf], hh, aH0);
      aH1 = MFMA(W.wH[1][kf], hh, aH1);
      aHn = MFMA(W.wH[2][kf], hh, aHn);
    }

    short4v ab, hb;
#pragma unroll
    for (int ri = 0; ri < 4; ++ri) {
      float rr = rcp_f(1.f + exp2_f(gA0[ri] + aH0[ri]));
      float zz = rcp_f(1.f + exp2_f(gA1[ri] + aH1[ri]));
      float en = exp2_f(fmaf(rr, aHn[ri], gAn[ri]));
      float nn = fmaf(-2.f, rcp_f(en + 1.f), 1.f);
      float hn = fmaf(zz, hprev[ri] - nn, nn);
      hprev[ri] = mk ? 0.f : hn;
      short bf = f2bf_s(hn);
      hb[ri] = mk ? (short)0 : bf;
      ab[ri] = bf;
    }

    if (t < T_STEPS - 1) {
      const short* xb = &s_x[(t + 1) & 3][lr * LSTR + lq * 8];
      f32x4 n0 = W.bRZ0v, n1 = W.bRZ1v, n2 = W.bNiv;
#pragma unroll
      for (int kf = 0; kf < 4; ++kf) {
        bf16x8 xh = *(const bf16x8*)(xb + kf * 32);
        n0 = MFMA(W.wI[0][kf], xh, n0);
        n1 = MFMA(W.wI[1][kf], xh, n1);
        n2 = MFMA(W.wI[2][kf], xh, n2);
      }
      gA0 = n0; gA1 = n1; gAn = n2;
    }

    *(short4v*)(dstb + (size_t)t * HID) = ab;
    *(short4v*)&s_h[p ^ 1][lr * LSTR + cb] = hb;
    if (t < T_STEPS - 2) {
      short4v c4 = {f2bf_s(pinf.x), f2bf_s(pinf.y), f2bf_s(pinf.z), f2bf_s(pinf.w)};
      *(short4v*)&s_x[(t + 2) & 3][srow * LSTR + scol] = c4;
    }
    asm volatile("s_waitcnt lgkmcnt(0)" ::: "memory");
    __builtin_amdgcn_s_barrier();
  }
}

// ---------------- layers 1,2: x direct from global (ws) ----------------
template <bool LASTL, int P>
__device__ __forceinline__ void cell_direct(
    int t, const unsigned short* xlane,
    bf16x8 (&xfill)[4], const bf16x8 (&xuse)[4],
    f32x4& gU0, f32x4& gU1, f32x4& gUn,
    f32x4& gW0, f32x4& gW1, f32x4& gWn,
    const LayerWB& W, float* dstf, unsigned short* dstb,
    unsigned mw0, unsigned mw1, short (*s_h)[RB * LSTR],
    int lr, int lq, int cb, float (&hprev)[4])
{
  // 1. issue direct loads of x(t+2) frags (global->reg, 4x16B)
  if (t < T_STEPS - 2) {
#pragma unroll
    for (int kf = 0; kf < 4; ++kf)
      xfill[kf] = *(const bf16x8*)(xlane + (size_t)(t + 2) * HID + kf * 32);
  }
  const int mk = (int)((((t & 32) ? mw1 : mw0) >> (t & 31)) & 1u);

  // 2. h-side MFMAs (barrier-dependent)
  f32x4 aH0 = (f32x4)(0.f), aH1 = (f32x4)(0.f), aHn = W.bNhv;
#pragma unroll
  for (int kf = 0; kf < 4; ++kf) {
    bf16x8 hh = *(const bf16x8*)&s_h[P][lr * LSTR + kf * 32 + lq * 8];
    aH0 = MFMA(W.wH[0][kf], hh, aH0);
    aH1 = MFMA(W.wH[1][kf], hh, aH1);
    aHn = MFMA(W.wH[2][kf], hh, aHn);
  }

  // 3. epilogue (consumes gA(t) = gU*)
  float4 actf;
  short4v ab, hb;
#pragma unroll
  for (int ri = 0; ri < 4; ++ri) {
    float rr = rcp_f(1.f + exp2_f(gU0[ri] + aH0[ri]));
    float zz = rcp_f(1.f + exp2_f(gU1[ri] + aH1[ri]));
    float en = exp2_f(fmaf(rr, aHn[ri], gUn[ri]));
    float nn = fmaf(-2.f, rcp_f(en + 1.f), 1.f);
    float hn = fmaf(zz, hprev[ri] - nn, nn);
    float hm = mk ? 0.f : hn;
    hprev[ri] = hm;
    short bf = f2bf_s(hn);
    hb[ri] = mk ? (short)0 : bf;
    if (LASTL) ((float*)&actf)[ri] = hm;  // masked y
    else       ab[ri] = bf;               // unmasked bf16 act
  }

  // 4. x-side MFMAs for t+1 from register frags (compiler inserts vmcnt)
  if (t < T_STEPS - 1) {
    gW0 = W.bRZ0v; gW1 = W.bRZ1v; gWn = W.bNiv;
#pragma unroll
    for (int kf = 0; kf < 4; ++kf) {
      gW0 = MFMA(W.wI[0][kf], xuse[kf], gW0);
      gW1 = MFMA(W.wI[1][kf], xuse[kf], gW1);
      gWn = MFMA(W.wI[2][kf], xuse[kf], gWn);
    }
  }

  // 5. stores: act (direct global), h (LDS)
  if (LASTL) *(float4*)(dstf + (size_t)t * HID) = actf;
  else       *(short4v*)(dstb + (size_t)t * HID) = ab;
  *(short4v*)&s_h[P ^ 1][lr * LSTR + cb] = hb;

  // 6. LDS-only sync; globals stay in flight
  asm volatile("s_waitcnt lgkmcnt(0)" ::: "memory");
  __builtin_amdgcn_s_barrier();
}

template <bool LASTL>
__device__ __forceinline__ void layer_direct(
    const LayerWB& W, const unsigned short* xlane,
    float* dstf, unsigned short* dstb,
    unsigned mw0, unsigned mw1, short (*s_h)[RB * LSTR],
    int tid, int lr, int lq, int cb)
{
  for (int i = tid; i < RB * LSTR; i += NTHR) s_h[0][i] = 0;

  // prologue: xE = x(0) frags, xO = x(1) frags; gA(0) into even regs
  bf16x8 xE[4], xO[4];
#pragma unroll
  for (int kf = 0; kf < 4; ++kf)
    xE[kf] = *(const bf16x8*)(xlane + kf * 32);
#pragma unroll
  for (int kf = 0; kf < 4; ++kf)
    xO[kf] = *(const bf16x8*)(xlane + (size_t)HID + kf * 32);

  f32x4 gAe0 = W.bRZ0v, gAe1 = W.bRZ1v, gAen = W.bNiv;
#pragma unroll
  for (int kf = 0; kf < 4; ++kf) {
    gAe0 = MFMA(W.wI[0][kf], xE[kf], gAe0);
    gAe1 = MFMA(W.wI[1][kf], xE[kf], gAe1);
    gAen = MFMA(W.wI[2][kf], xE[kf], gAen);
  }
  f32x4 gAo0, gAo1, gAon;
  float hprev[4] = {0.f, 0.f, 0.f, 0.f};
  __syncthreads();

  for (int t2 = 0; t2 < T_STEPS; t2 += 2) {
    // even cell: uses gA-even, consumes xO (=x(t+1)), refills xE (=x(t+2))
    cell_direct<LASTL, 0>(t2, xlane, xE, xO, gAe0, gAe1, gAen,
                          gAo0, gAo1, gAon, W, dstf, dstb,
                          mw0, mw1, s_h, lr, lq, cb, hprev);
    // odd cell: uses gA-odd, consumes xE, refills xO
    cell_direct<LASTL, 1>(t2 + 1, xlane, xO, xE, gAo0, gAo1, gAon,
                          gAe0, gAe1, gAen, W, dstf, dstb,
                          mw0, mw1, s_h, lr, lq, cb, hprev);
  }
}

__global__ __launch_bounds__(NTHR, 1) void gru15(
    const float* __restrict__ x, const int* __restrict__ invalid,
    const float* __restrict__ w_ih, const float* __restrict__ w_hh,
    const float* __restrict__ b_ih, const float* __restrict__ b_hh,
    float* out, unsigned short* ws)
{
  __shared__ short s_x[4][RB * LSTR];  // L0 x ring only
  __shared__ short s_h[2][RB * LSTR];
  __shared__ unsigned s_mw[RB * 2];

  const int tid = threadIdx.x;
  const int wave = tid >> 6, lane = tid & 63;
  const int lr = lane & 15, lq = lane >> 4;
  const int row_base = (int)blockIdx.x * RB;
  const int srow = tid >> 5, scol = (tid & 31) * 4;
  const int cb = wave * 16 + lq * 4;

  // ---- pack invalid -> 2 u32 words per row via ballot (once) ----
  {
    const int rr = 2 * wave + (lane >> 5);
    const int tt = lane & 31;
    const size_t base = (size_t)(row_base + rr) * T_STEPS;
    unsigned long long b1 = __ballot(invalid[base + tt] != 0);
    unsigned long long b2 = __ballot(invalid[base + 32 + tt] != 0);
    if (lane == 0) {
      s_mw[(2 * wave) * 2]         = (unsigned)b1;
      s_mw[(2 * wave + 1) * 2]     = (unsigned)(b1 >> 32);
      s_mw[(2 * wave) * 2 + 1]     = (unsigned)b2;
      s_mw[(2 * wave + 1) * 2 + 1] = (unsigned)(b2 >> 32);
    }
  }
  __syncthreads();
  const unsigned mw0 = s_mw[lr * 2], mw1 = s_mw[lr * 2 + 1];

  const size_t soff = (size_t)(row_base + srow) * T_STEPS * HID + scol;  // staging
  const size_t doff = (size_t)(row_base + lr) * T_STEPS * HID + cb;      // scatter
  const unsigned short* xlane = ws + (size_t)(row_base + lr) * T_STEPS * HID + lq * 8;

  LayerWB W;
  // L0: f32 x (staged LDS) -> bf16 ws acts
  load_weights(W, w_ih, w_hh, b_ih, b_hh, wave, lr, lq, cb);
  layer0_pass(W, x + soff, ws + doff, mw0, mw1, s_x, s_h,
              tid, lr, lq, srow, scol, cb);
  __syncthreads();  // drain: ws visible before L1 reads it
  // L1: ws bf16 direct -> ws bf16 (in-place; load(t) waited 1 cell pre-store)
  load_weights(W, w_ih + 3 * HID * HID, w_hh + 3 * HID * HID,
               b_ih + 3 * HID, b_hh + 3 * HID, wave, lr, lq, cb);
  layer_direct<false>(W, xlane, nullptr, ws + doff, mw0, mw1, s_h, tid, lr, lq, cb);
  __syncthreads();
  // L2: ws bf16 direct -> f32 out (masked y)
  load_weights(W, w_ih + 6 * HID * HID, w_hh + 6 * HID * HID,
               b_ih + 6 * HID, b_hh + 6 * HID, wave, lr, lq, cb);
  layer_direct<true>(W, xlane, out + doff, nullptr, mw0, mw1, s_h, tid, lr, lq, cb);
}

extern "C" void kernel_launch(void* const* d_in, const int* in_sizes, int n_in,
                              void* d_out, int out_size, void* d_ws, size_t ws_size,
                              hipStream_t stream) {
  const float* x       = (const float*)d_in[0];
  const int*   invalid = (const int*)d_in[1];
  const float* w_ih    = (const float*)d_in[2];
  const float* w_hh    = (const float*)d_in[3];
  const float* b_ih    = (const float*)d_in[4];
  const float* b_hh    = (const float*)d_in[5];
  gru15<<<dim3(NBLK), dim3(NTHR), 0, stream>>>(x, invalid, w_ih, w_hh, b_ih, b_hh,
                                               (float*)d_out, (unsigned short*)d_ws);
}

// Round 16
// 228.701 us; speedup vs baseline: 1.1841x; 1.1841x over previous
//
#include <hip/hip_runtime.h>
#include <hip/hip_bf16.h>

// MultiAgentGRULoop round 16: R14 (best, 214us) + micro-trims.
//   - h ds_write hoisted before the x-MFMA cluster (write latency drains
//     under MFMA issue instead of on the cell-end lgkmcnt chain).
//   - Explicit 2-cell unrolled t-loop, template<P> parity -> all s_h buffer
//     selects are compile-time immediates.
//   - Everything else byte-identical to R14: 256x512, bounds(512,1),
//     swapped-operand MFMA D[gate][row], register-resident weights, f32
//     register h recurrence, rcp/exp2 epilogue with folded gate scaling,
//     bf16 inter-layer acts in d_ws, ballot-packed masks, direct 64B-line
//     act stores, x 4-slot LDS ring staged 2 ahead, lgkm-only barrier.

#define T_STEPS 64
#define HID 128
#define NL 3
#define RB 16
#define NTHR 512
#define NBLK 256
#define LSTR 136   // bf16 x/h row stride (shorts): 272 B, 16B-aligned

typedef __attribute__((ext_vector_type(8))) short bf16x8;
typedef __attribute__((ext_vector_type(4))) short short4v;
typedef __attribute__((ext_vector_type(4))) float f32x4;

static __device__ __forceinline__ short f2bf_s(float f) {
  __hip_bfloat16 b = __float2bfloat16(f);
  return __builtin_bit_cast(short, b);
}
static __device__ __forceinline__ float rcp_f(float x) {
  float r; asm("v_rcp_f32 %0, %1" : "=v"(r) : "v"(x)); return r;
}
static __device__ __forceinline__ float exp2_f(float x) {
  float r; asm("v_exp_f32 %0, %1" : "=v"(r) : "v"(x)); return r;
}

#define MFMA(A, B, C) __builtin_amdgcn_mfma_f32_16x16x32_bf16((A), (B), (C), 0, 0, 0)

#define NL2E  (-1.4426950408889634f)   // -log2(e)
#define T2L2E (2.8853900817779268f)    // 2*log2(e)

struct LayerWB {
  bf16x8 wI[3][4], wH[3][4];
  f32x4 bRZ0v, bRZ1v, bNiv, bNhv;
};

__device__ __forceinline__ void load_weights(
    LayerWB& W, const float* wih, const float* whh,
    const float* bih, const float* bhh, int wave, int lr, int lq, int cb)
{
#pragma unroll
  for (int g = 0; g < 3; ++g) {
    const float sc = (g < 2) ? NL2E : T2L2E;
#pragma unroll
    for (int kf = 0; kf < 4; ++kf) {
      const int wrow = g * HID + wave * 16 + lr;
      const int kofs = kf * 32 + lq * 8;
      const float* pI = wih + (size_t)wrow * HID + kofs;
      const float* pH = whh + (size_t)wrow * HID + kofs;
      float4 a = *(const float4*)pI, b = *(const float4*)(pI + 4);
      float vi[8] = {a.x, a.y, a.z, a.w, b.x, b.y, b.z, b.w};
      float4 c = *(const float4*)pH, d = *(const float4*)(pH + 4);
      float vh[8] = {c.x, c.y, c.z, c.w, d.x, d.y, d.z, d.w};
#pragma unroll
      for (int j = 0; j < 8; ++j) {
        W.wI[g][kf][j] = f2bf_s(sc * vi[j]);
        W.wH[g][kf][j] = f2bf_s(sc * vh[j]);
      }
    }
  }
#pragma unroll
  for (int ri = 0; ri < 4; ++ri) {
    const int c = cb + ri;
    W.bRZ0v[ri] = NL2E * (bih[c] + bhh[c]);
    W.bRZ1v[ri] = NL2E * (bih[HID + c] + bhh[HID + c]);
    W.bNiv[ri]  = T2L2E * bih[2 * HID + c];
    W.bNhv[ri]  = T2L2E * bhh[2 * HID + c];
  }
}

// one GRU cell; P = compile-time parity of s_h buffers
template <bool SRCBF, bool LASTL, int P>
__device__ __forceinline__ void cell(
    int t, const LayerWB& W,
    const float* srcf, const unsigned short* srcb,
    float* dstf, unsigned short* dstb,
    unsigned mw0, unsigned mw1,
    short (*s_x)[RB * LSTR], short (*s_h)[RB * LSTR],
    int lr, int lq, int srow, int scol, int cb,
    f32x4& gA0, f32x4& gA1, f32x4& gAn, float (&hprev)[4])
{
  // 1. issue x(t+2) load (consumed at staging, end of cell)
  float4 pinf;
  short4v pinb;
  if (t < T_STEPS - 2) {
    if (SRCBF) pinb = *(const short4v*)(srcb + (size_t)(t + 2) * HID);
    else       pinf = *(const float4*)(srcf + (size_t)(t + 2) * HID);
  }
  const int mk = (int)((((t & 32) ? mw1 : mw0) >> (t & 31)) & 1u);

  // 2. h-side MFMAs (the only barrier-dependent ones)
  f32x4 aH0 = (f32x4)(0.f), aH1 = (f32x4)(0.f), aHn = W.bNhv;
#pragma unroll
  for (int kf = 0; kf < 4; ++kf) {
    bf16x8 hh = *(const bf16x8*)&s_h[P][lr * LSTR + kf * 32 + lq * 8];
    aH0 = MFMA(W.wH[0][kf], hh, aH0);
    aH1 = MFMA(W.wH[1][kf], hh, aH1);
    aHn = MFMA(W.wH[2][kf], hh, aHn);
  }

  // 3. epilogue (consumes gA of step t)
  float4 actf;
  short4v ab, hb;
#pragma unroll
  for (int ri = 0; ri < 4; ++ri) {
    float rr = rcp_f(1.f + exp2_f(gA0[ri] + aH0[ri]));   // sigmoid (folded)
    float zz = rcp_f(1.f + exp2_f(gA1[ri] + aH1[ri]));
    float en = exp2_f(fmaf(rr, aHn[ri], gAn[ri]));       // 2^(2*log2e*u)
    float nn = fmaf(-2.f, rcp_f(en + 1.f), 1.f);         // tanh(u)
    float hn = fmaf(zz, hprev[ri] - nn, nn);
    float hm = mk ? 0.f : hn;
    hprev[ri] = hm;
    short bf = f2bf_s(hn);
    hb[ri] = mk ? (short)0 : bf;
    if (LASTL) ((float*)&actf)[ri] = hm;  // masked y
    else       ab[ri] = bf;               // unmasked bf16 act
  }
  // h write EARLY: drains under the x-MFMA cluster below
  *(short4v*)&s_h[P ^ 1][lr * LSTR + cb] = hb;

  // 4. x-side MFMAs for t+1 (independent; interleaves with epilogue tail)
  if (t < T_STEPS - 1) {
    const short* xb = &s_x[(t + 1) & 3][lr * LSTR + lq * 8];
    f32x4 n0 = W.bRZ0v, n1 = W.bRZ1v, n2 = W.bNiv;
#pragma unroll
    for (int kf = 0; kf < 4; ++kf) {
      bf16x8 xh = *(const bf16x8*)(xb + kf * 32);
      n0 = MFMA(W.wI[0][kf], xh, n0);
      n1 = MFMA(W.wI[1][kf], xh, n1);
      n2 = MFMA(W.wI[2][kf], xh, n2);
    }
    gA0 = n0; gA1 = n1; gAn = n2;
  }

  // 5. act store (direct global, 64B-line tiled) + x-stage
  if (LASTL) *(float4*)(dstf + (size_t)t * HID) = actf;
  else       *(short4v*)(dstb + (size_t)t * HID) = ab;
  if (t < T_STEPS - 2) {
    if (SRCBF) {
      *(short4v*)&s_x[(t + 2) & 3][srow * LSTR + scol] = pinb;
    } else {
      short4v c4 = {f2bf_s(pinf.x), f2bf_s(pinf.y), f2bf_s(pinf.z), f2bf_s(pinf.w)};
      *(short4v*)&s_x[(t + 2) & 3][srow * LSTR + scol] = c4;
    }
  }
  // 6. LDS-only sync; globals stay in flight
  asm volatile("s_waitcnt lgkmcnt(0)" ::: "memory");
  __builtin_amdgcn_s_barrier();
}

template <bool SRCBF, bool LASTL>
__device__ __forceinline__ void layer_pass(
    const LayerWB& W,
    const float* srcf, const unsigned short* srcb,
    float* dstf, unsigned short* dstb,
    unsigned mw0, unsigned mw1,
    short (*s_x)[RB * LSTR], short (*s_h)[RB * LSTR],
    int tid, int lr, int lq, int srow, int scol, int cb)
{
  // ---- h := 0; stage x(0)->slot0, x(1)->slot1 ----
  for (int i = tid; i < RB * LSTR; i += NTHR) s_h[0][i] = 0;
#pragma unroll
  for (int st = 0; st < 2; ++st) {
    if (SRCBF) {
      *(short4v*)&s_x[st][srow * LSTR + scol] = *(const short4v*)(srcb + (size_t)st * HID);
    } else {
      float4 v = *(const float4*)(srcf + (size_t)st * HID);
      short4v c4 = {f2bf_s(v.x), f2bf_s(v.y), f2bf_s(v.z), f2bf_s(v.w)};
      *(short4v*)&s_x[st][srow * LSTR + scol] = c4;
    }
  }
  __syncthreads();

  // ---- prologue: gA(0) from slot 0 ----
  f32x4 gA0 = W.bRZ0v, gA1 = W.bRZ1v, gAn = W.bNiv;
#pragma unroll
  for (int kf = 0; kf < 4; ++kf) {
    bf16x8 xh = *(const bf16x8*)&s_x[0][lr * LSTR + kf * 32 + lq * 8];
    gA0 = MFMA(W.wI[0][kf], xh, gA0);
    gA1 = MFMA(W.wI[1][kf], xh, gA1);
    gAn = MFMA(W.wI[2][kf], xh, gAn);
  }
  float hprev[4] = {0.f, 0.f, 0.f, 0.f};

  // ---- main loop: 2 cells per iteration, compile-time parity ----
  for (int t2 = 0; t2 < T_STEPS; t2 += 2) {
    cell<SRCBF, LASTL, 0>(t2, W, srcf, srcb, dstf, dstb, mw0, mw1,
                          s_x, s_h, lr, lq, srow, scol, cb, gA0, gA1, gAn, hprev);
    cell<SRCBF, LASTL, 1>(t2 + 1, W, srcf, srcb, dstf, dstb, mw0, mw1,
                          s_x, s_h, lr, lq, srow, scol, cb, gA0, gA1, gAn, hprev);
  }
}

__global__ __launch_bounds__(NTHR, 1) void gru16(
    const float* __restrict__ x, const int* __restrict__ invalid,
    const float* __restrict__ w_ih, const float* __restrict__ w_hh,
    const float* __restrict__ b_ih, const float* __restrict__ b_hh,
    float* out, unsigned short* ws)
{
  __shared__ short s_x[4][RB * LSTR];  // x bf16 4-slot ring (slot = t&3)
  __shared__ short s_h[2][RB * LSTR];  // h bf16 (masked), dbuf
  __shared__ unsigned s_mw[RB * 2];

  const int tid = threadIdx.x;
  const int wave = tid >> 6, lane = tid & 63;
  const int lr = lane & 15, lq = lane >> 4;
  const int row_base = (int)blockIdx.x * RB;
  const int srow = tid >> 5, scol = (tid & 31) * 4;  // coalesced staging map
  const int cb = wave * 16 + lq * 4;                 // epilogue col base

  // ---- pack invalid -> 2 u32 words per row via ballot (once) ----
  {
    const int rr = 2 * wave + (lane >> 5);
    const int tt = lane & 31;
    const size_t base = (size_t)(row_base + rr) * T_STEPS;
    unsigned long long b1 = __ballot(invalid[base + tt] != 0);
    unsigned long long b2 = __ballot(invalid[base + 32 + tt] != 0);
    if (lane == 0) {
      s_mw[(2 * wave) * 2]         = (unsigned)b1;
      s_mw[(2 * wave + 1) * 2]     = (unsigned)(b1 >> 32);
      s_mw[(2 * wave) * 2 + 1]     = (unsigned)b2;
      s_mw[(2 * wave + 1) * 2 + 1] = (unsigned)(b2 >> 32);
    }
  }
  __syncthreads();
  const unsigned mw0 = s_mw[lr * 2], mw1 = s_mw[lr * 2 + 1];

  const size_t soff = (size_t)(row_base + srow) * T_STEPS * HID + scol;  // staging
  const size_t doff = (size_t)(row_base + lr) * T_STEPS * HID + cb;      // scatter

  LayerWB W;
  // L0: f32 x -> bf16 ws (unmasked acts)
  load_weights(W, w_ih, w_hh, b_ih, b_hh, wave, lr, lq, cb);
  layer_pass<false, false>(W, x + soff, nullptr, nullptr, ws + doff,
                           mw0, mw1, s_x, s_h, tid, lr, lq, srow, scol, cb);
  __syncthreads();  // full drain: ws visible before L1 stages it
  // L1: bf16 ws -> bf16 ws (in-place; reads lead writes by >=2 barriers)
  load_weights(W, w_ih + 3 * HID * HID, w_hh + 3 * HID * HID,
               b_ih + 3 * HID, b_hh + 3 * HID, wave, lr, lq, cb);
  layer_pass<true, false>(W, nullptr, ws + soff, nullptr, ws + doff,
                          mw0, mw1, s_x, s_h, tid, lr, lq, srow, scol, cb);
  __syncthreads();
  // L2: bf16 ws -> f32 out (masked y)
  load_weights(W, w_ih + 6 * HID * HID, w_hh + 6 * HID * HID,
               b_ih + 6 * HID, b_hh + 6 * HID, wave, lr, lq, cb);
  layer_pass<true, true>(W, nullptr, ws + soff, out + doff, nullptr,
                         mw0, mw1, s_x, s_h, tid, lr, lq, srow, scol, cb);
}

extern "C" void kernel_launch(void* const* d_in, const int* in_sizes, int n_in,
                              void* d_out, int out_size, void* d_ws, size_t ws_size,
                              hipStream_t stream) {
  const float* x       = (const float*)d_in[0];
  const int*   invalid = (const int*)d_in[1];
  const float* w_ih    = (const float*)d_in[2];
  const float* w_hh    = (const float*)d_in[3];
  const float* b_ih    = (const float*)d_in[4];
  const float* b_hh    = (const float*)d_in[5];
  gru16<<<dim3(NBLK), dim3(NTHR), 0, stream>>>(x, invalid, w_ih, w_hh, b_ih, b_hh,
                                               (float*)d_out, (unsigned short*)d_ws);
}

// Round 17
// 213.396 us; speedup vs baseline: 1.2690x; 1.0717x over previous
//
#include <hip/hip_runtime.h>
#include <hip/hip_bf16.h>

// MultiAgentGRULoop FINAL (revert to round 14 — measured best, 214.1 us).
//   R16's micro-trims (early h-write + template<P> 2-cell unroll) regressed
//   -7% (codegen perturbation: both MfmaUtil and VALUBusy DROPPED with same
//   work). This is R14 byte-for-byte.
//
//   Structure (the measured optimum of this design space, R1->R16):
//   - 256 blocks x 512 thr (8 waves), 1 block/CU, bounds(512,1): the only
//     envelope that holds the 96-reg full-k weight slice without spilling
//     (R5/R7/R8 spilled at >8 waves/CU; R9's P/C split lost on LDS traffic).
//   - Layer-outer; block owns 16 batch rows end-to-end; bf16 inter-layer
//     acts in d_ws (pure short4 restage, zero converts for layers 1-2).
//   - Swapped-operand MFMA D[gate_col][act_row]; register-resident Wi/Wh
//     (bf16 frags, k-map kf*32+lq*8); biases folded into MFMA C-init with
//     exp2 scaling folded into the weights (sigmoid = rcp(1+exp2(s)),
//     tanh = fma(-2, rcp(exp2(2u*log2e)+1), 1)); h recurrence in f32 regs.
//   - Cell t: issue x(t+2) load -> h-MFMA(12) -> epilogue(t) (rcp/exp2)
//     || x-MFMA(t+1) into carried gA regs -> direct 64B-line act store +
//     h ds_write + x-ring stage -> lgkmcnt-only s_barrier (globals stay
//     in flight; vmcnt(0) drains only at layer boundaries).
//   - invalid masks ballot-packed into 2 u32/thread (no per-cell ds_read).

#define T_STEPS 64
#define HID 128
#define NL 3
#define RB 16
#define NTHR 512
#define NBLK 256
#define LSTR 136   // bf16 x/h row stride (shorts): 272 B, 16B-aligned

typedef __attribute__((ext_vector_type(8))) short bf16x8;
typedef __attribute__((ext_vector_type(4))) short short4v;
typedef __attribute__((ext_vector_type(4))) float f32x4;

static __device__ __forceinline__ short f2bf_s(float f) {
  __hip_bfloat16 b = __float2bfloat16(f);
  return __builtin_bit_cast(short, b);
}
static __device__ __forceinline__ float rcp_f(float x) {
  float r; asm("v_rcp_f32 %0, %1" : "=v"(r) : "v"(x)); return r;
}
static __device__ __forceinline__ float exp2_f(float x) {
  float r; asm("v_exp_f32 %0, %1" : "=v"(r) : "v"(x)); return r;
}

#define MFMA(A, B, C) __builtin_amdgcn_mfma_f32_16x16x32_bf16((A), (B), (C), 0, 0, 0)

#define NL2E  (-1.4426950408889634f)   // -log2(e)
#define T2L2E (2.8853900817779268f)    // 2*log2(e)

template <bool SRCBF, bool LASTL>
__device__ __forceinline__ void layer_pass(
    const float* __restrict__ wih, const float* __restrict__ whh,
    const float* __restrict__ bih, const float* __restrict__ bhh,
    const float* srcf, const unsigned short* srcb,
    float* dstf, unsigned short* dstb,
    unsigned mw0, unsigned mw1,
    short (*s_x)[RB * LSTR], short (*s_h)[RB * LSTR],
    int tid, int wave, int lr, int lq, int srow, int scol, int cb)
{
  // ---- weights -> bf16 register fragments, exp2 scaling folded in ----
  bf16x8 wI[3][4], wH[3][4];
#pragma unroll
  for (int g = 0; g < 3; ++g) {
    const float sc = (g < 2) ? NL2E : T2L2E;
#pragma unroll
    for (int kf = 0; kf < 4; ++kf) {
      const int wrow = g * HID + wave * 16 + lr;
      const int kofs = kf * 32 + lq * 8;
      const float* pI = wih + (size_t)wrow * HID + kofs;
      const float* pH = whh + (size_t)wrow * HID + kofs;
      float4 a = *(const float4*)pI, b = *(const float4*)(pI + 4);
      float vi[8] = {a.x, a.y, a.z, a.w, b.x, b.y, b.z, b.w};
      float4 c = *(const float4*)pH, d = *(const float4*)(pH + 4);
      float vh[8] = {c.x, c.y, c.z, c.w, d.x, d.y, d.z, d.w};
#pragma unroll
      for (int j = 0; j < 8; ++j) {
        wI[g][kf][j] = f2bf_s(sc * vi[j]);
        wH[g][kf][j] = f2bf_s(sc * vh[j]);
      }
    }
  }
  f32x4 bRZ0v, bRZ1v, bNiv, bNhv;
#pragma unroll
  for (int ri = 0; ri < 4; ++ri) {
    const int c = cb + ri;
    bRZ0v[ri] = NL2E * (bih[c] + bhh[c]);
    bRZ1v[ri] = NL2E * (bih[HID + c] + bhh[HID + c]);
    bNiv[ri]  = T2L2E * bih[2 * HID + c];
    bNhv[ri]  = T2L2E * bhh[2 * HID + c];
  }

  // ---- h := 0; stage x(0)->slot0, x(1)->slot1 ----
  for (int i = tid; i < RB * LSTR; i += NTHR) s_h[0][i] = 0;
#pragma unroll
  for (int st = 0; st < 2; ++st) {
    if (SRCBF) {
      *(short4v*)&s_x[st][srow * LSTR + scol] = *(const short4v*)(srcb + (size_t)st * HID);
    } else {
      float4 v = *(const float4*)(srcf + (size_t)st * HID);
      short4v c4 = {f2bf_s(v.x), f2bf_s(v.y), f2bf_s(v.z), f2bf_s(v.w)};
      *(short4v*)&s_x[st][srow * LSTR + scol] = c4;
    }
  }
  __syncthreads();

  // ---- prologue: gA(0) from slot 0 ----
  f32x4 gA0 = bRZ0v, gA1 = bRZ1v, gAn = bNiv;
#pragma unroll
  for (int kf = 0; kf < 4; ++kf) {
    bf16x8 xh = *(const bf16x8*)&s_x[0][lr * LSTR + kf * 32 + lq * 8];
    gA0 = MFMA(wI[0][kf], xh, gA0);
    gA1 = MFMA(wI[1][kf], xh, gA1);
    gAn = MFMA(wI[2][kf], xh, gAn);
  }
  float hprev[4] = {0.f, 0.f, 0.f, 0.f};

  for (int t = 0; t < T_STEPS; ++t) {
    const int p = t & 1;
    // ---- issue x(t+2) load (consumed at staging, end of cell) ----
    float4 pinf;
    short4v pinb;
    if (t < T_STEPS - 2) {
      if (SRCBF) pinb = *(const short4v*)(srcb + (size_t)(t + 2) * HID);
      else       pinf = *(const float4*)(srcf + (size_t)(t + 2) * HID);
    }
    const int mk = (int)((((t & 32) ? mw1 : mw0) >> (t & 31)) & 1u);

    // ---- h-side MFMAs (the only barrier-dependent ones) ----
    f32x4 aH0 = (f32x4)(0.f), aH1 = (f32x4)(0.f), aHn = bNhv;
#pragma unroll
    for (int kf = 0; kf < 4; ++kf) {
      bf16x8 hh = *(const bf16x8*)&s_h[p][lr * LSTR + kf * 32 + lq * 8];
      aH0 = MFMA(wH[0][kf], hh, aH0);
      aH1 = MFMA(wH[1][kf], hh, aH1);
      aHn = MFMA(wH[2][kf], hh, aHn);
    }

    // ---- epilogue (consumes gA of step t) ----
    float4 actf;
    short4v ab, hb;
#pragma unroll
    for (int ri = 0; ri < 4; ++ri) {
      float rr = rcp_f(1.f + exp2_f(gA0[ri] + aH0[ri]));   // sigmoid (folded)
      float zz = rcp_f(1.f + exp2_f(gA1[ri] + aH1[ri]));
      float en = exp2_f(fmaf(rr, aHn[ri], gAn[ri]));       // 2^(2*log2e*u)
      float nn = fmaf(-2.f, rcp_f(en + 1.f), 1.f);         // tanh(u)
      float hn = fmaf(zz, hprev[ri] - nn, nn);
      float hm = mk ? 0.f : hn;
      hprev[ri] = hm;
      short bf = f2bf_s(hn);
      hb[ri] = mk ? (short)0 : bf;
      if (LASTL) ((float*)&actf)[ri] = hm;  // masked y
      else       ab[ri] = bf;               // unmasked bf16 act
    }

    // ---- x-side MFMAs for t+1 (independent; interleaves with epilogue) ----
    if (t < T_STEPS - 1) {
      const short* xb = &s_x[(t + 1) & 3][lr * LSTR + lq * 8];
      f32x4 n0 = bRZ0v, n1 = bRZ1v, n2 = bNiv;
#pragma unroll
      for (int kf = 0; kf < 4; ++kf) {
        bf16x8 xh = *(const bf16x8*)(xb + kf * 32);
        n0 = MFMA(wI[0][kf], xh, n0);
        n1 = MFMA(wI[1][kf], xh, n1);
        n2 = MFMA(wI[2][kf], xh, n2);
      }
      gA0 = n0; gA1 = n1; gAn = n2;
    }

    // ---- writes: act (direct global), h (LDS), x-stage (LDS ring) ----
    if (LASTL) *(float4*)(dstf + (size_t)t * HID) = actf;
    else       *(short4v*)(dstb + (size_t)t * HID) = ab;
    *(short4v*)&s_h[p ^ 1][lr * LSTR + cb] = hb;
    if (t < T_STEPS - 2) {
      if (SRCBF) {
        *(short4v*)&s_x[(t + 2) & 3][srow * LSTR + scol] = pinb;
      } else {
        short4v c4 = {f2bf_s(pinf.x), f2bf_s(pinf.y), f2bf_s(pinf.z), f2bf_s(pinf.w)};
        *(short4v*)&s_x[(t + 2) & 3][srow * LSTR + scol] = c4;
      }
    }
    // ---- LDS-only sync; globals stay in flight ----
    asm volatile("s_waitcnt lgkmcnt(0)" ::: "memory");
    __builtin_amdgcn_s_barrier();
  }
}

__global__ __launch_bounds__(NTHR, 1) void gru14(
    const float* __restrict__ x, const int* __restrict__ invalid,
    const float* __restrict__ w_ih, const float* __restrict__ w_hh,
    const float* __restrict__ b_ih, const float* __restrict__ b_hh,
    float* out, unsigned short* ws)
{
  __shared__ short s_x[4][RB * LSTR];  // x bf16 4-slot ring (slot = t&3)
  __shared__ short s_h[2][RB * LSTR];  // h bf16 (masked), dbuf
  __shared__ unsigned s_mw[RB * 2];

  const int tid = threadIdx.x;
  const int wave = tid >> 6, lane = tid & 63;
  const int lr = lane & 15, lq = lane >> 4;
  const int row_base = (int)blockIdx.x * RB;
  const int srow = tid >> 5, scol = (tid & 31) * 4;  // coalesced staging map
  const int cb = wave * 16 + lq * 4;                 // epilogue col base

  // ---- pack invalid -> 2 u32 words per row via ballot (once) ----
  {
    const int rr = 2 * wave + (lane >> 5);
    const int tt = lane & 31;
    const size_t base = (size_t)(row_base + rr) * T_STEPS;
    unsigned long long b1 = __ballot(invalid[base + tt] != 0);
    unsigned long long b2 = __ballot(invalid[base + 32 + tt] != 0);
    if (lane == 0) {
      s_mw[(2 * wave) * 2]         = (unsigned)b1;
      s_mw[(2 * wave + 1) * 2]     = (unsigned)(b1 >> 32);
      s_mw[(2 * wave) * 2 + 1]     = (unsigned)b2;
      s_mw[(2 * wave + 1) * 2 + 1] = (unsigned)(b2 >> 32);
    }
  }
  __syncthreads();
  const unsigned mw0 = s_mw[lr * 2], mw1 = s_mw[lr * 2 + 1];

  const size_t soff = (size_t)(row_base + srow) * T_STEPS * HID + scol;  // staging
  const size_t doff = (size_t)(row_base + lr) * T_STEPS * HID + cb;      // scatter

  // L0: f32 x -> bf16 ws (unmasked acts)
  layer_pass<false, false>(w_ih, w_hh, b_ih, b_hh,
                           x + soff, nullptr, nullptr, ws + doff,
                           mw0, mw1, s_x, s_h, tid, wave, lr, lq, srow, scol, cb);
  __syncthreads();  // full drain: ws visible before L1 stages it
  // L1: bf16 ws -> bf16 ws (in-place; reads lead writes by >=2 barriers)
  layer_pass<true, false>(w_ih + 3 * HID * HID, w_hh + 3 * HID * HID,
                          b_ih + 3 * HID, b_hh + 3 * HID,
                          nullptr, ws + soff, nullptr, ws + doff,
                          mw0, mw1, s_x, s_h, tid, wave, lr, lq, srow, scol, cb);
  __syncthreads();
  // L2: bf16 ws -> f32 out (masked y)
  layer_pass<true, true>(w_ih + 6 * HID * HID, w_hh + 6 * HID * HID,
                         b_ih + 6 * HID, b_hh + 6 * HID,
                         nullptr, ws + soff, out + doff, nullptr,
                         mw0, mw1, s_x, s_h, tid, wave, lr, lq, srow, scol, cb);
}

extern "C" void kernel_launch(void* const* d_in, const int* in_sizes, int n_in,
                              void* d_out, int out_size, void* d_ws, size_t ws_size,
                              hipStream_t stream) {
  const float* x       = (const float*)d_in[0];
  const int*   invalid = (const int*)d_in[1];
  const float* w_ih    = (const float*)d_in[2];
  const float* w_hh    = (const float*)d_in[3];
  const float* b_ih    = (const float*)d_in[4];
  const float* b_hh    = (const float*)d_in[5];
  gru14<<<dim3(NBLK), dim3(NTHR), 0, stream>>>(x, invalid, w_ih, w_hh, b_ih, b_hh,
                                               (float*)d_out, (unsigned short*)d_ws);
}